// Round 5
// baseline (123.617 us; speedup 1.0000x reference)
//
#include <hip/hip_runtime.h>
#include <math.h>

// StructureLoss — fused kernel, R5: occupancy + load-pipeline depth.
// R4 post-mortem: sloss_main 42 us, FETCH 106 MB @ 2.6 TB/s (32%), VALU 24%,
// Occ 27% -> latency-bound, NOT LDS-issue-bound (prefix rewrite was neutral).
// R5: RG 16->8 with 128-thread blocks -> grid 2048 (8 blocks/CU, 16 waves/CU),
// LDS 18.4 KB; stage-1 owns 4 cols/thread via float4 loads with
// __launch_bounds__(128,4) (VGPR cap 128) for deep in-flight load pipelining.

#define IMG_H 512
#define IMG_W 512
#define NB    32
#define HW    (IMG_H * IMG_W)
#define RG    8               // output rows per block
#define NGRP  (IMG_H / RG)    // 64 row-groups per image
#define NTH   128
#define VST   576             // LDS row stride (floats); 512 + 16*4 skew

// skew +4 floats per 32-col chunk: chunk s occupies [36s, 36s+31] -> each
// 32-float chunk contiguous & 16B-aligned.
__device__ __forceinline__ int vidx(int c) { return c + 4 * (c >> 5); }

__device__ __forceinline__ float wave_reduce(float v) {
#pragma unroll
  for (int off = 32; off > 0; off >>= 1) v += __shfl_down(v, off, 64);
  return v;
}

__global__ __launch_bounds__(NTH, 4) void sloss_main(const float* __restrict__ x,
                                                     const float* __restrict__ t,
                                                     float* __restrict__ part) {
  __shared__ float vls[RG * VST];   // 8*576*4 = 18432 B -> 8 blocks/CU
  __shared__ float red[2][4];

  const int tid = threadIdx.x;
  const int img = blockIdx.x >> 6;
  const int grp = blockIdx.x & 63;
  const int r0  = grp * RG;
  const float* tb = t + (size_t)img * HW;
  const float* xb = x + (size_t)img * HW;

  // ---- Stage 1: vertical 31-row running sums; thread owns cols 4t..4t+3 ----
  {
    const float4* tc4 = (const float4*)tb + tid;   // row stride = 128 float4
    const int li = vidx(4 * tid);                  // 16B-aligned, one chunk
    float s0 = 0.f, s1 = 0.f, s2 = 0.f, s3 = 0.f;
    if (grp >= 2 && grp <= 61) {                   // interior: no row guards
#pragma unroll
      for (int k = -15; k < 15; ++k) {
        float4 v = tc4[(r0 + k) * 128];
        s0 += v.x; s1 += v.y; s2 += v.z; s3 += v.w;
      }
#pragma unroll
      for (int i = 0; i < RG; ++i) {
        float4 v = tc4[(r0 + i + 15) * 128];
        s0 += v.x; s1 += v.y; s2 += v.z; s3 += v.w;
        *(float4*)(vls + i * VST + li) = float4{s0, s1, s2, s3};
        float4 u = tc4[(r0 + i - 15) * 128];
        s0 -= u.x; s1 -= u.y; s2 -= u.z; s3 -= u.w;
      }
    } else {                                       // edge groups: guarded
#pragma unroll
      for (int k = -15; k < 15; ++k) {
        int r = r0 + k;
        if ((unsigned)r < IMG_H) {
          float4 v = tc4[r * 128];
          s0 += v.x; s1 += v.y; s2 += v.z; s3 += v.w;
        }
      }
#pragma unroll
      for (int i = 0; i < RG; ++i) {
        int ra = r0 + i + 15;
        if (ra < IMG_H) {
          float4 v = tc4[ra * 128];
          s0 += v.x; s1 += v.y; s2 += v.z; s3 += v.w;
        }
        *(float4*)(vls + i * VST + li) = float4{s0, s1, s2, s3};
        int rs = r0 + i - 15;
        if (rs >= 0) {
          float4 u = tc4[rs * 128];
          s0 -= u.x; s1 -= u.y; s2 -= u.z; s3 -= u.w;
        }
      }
    }
  }
  __syncthreads();

  // ---- Stage 2: row prefix sums + box from registers + fused elementwise ----
  const int row = tid >> 4;                 // 0..7
  const int sub = tid & 15;                 // 0..15 (32-col chunk)
  const int c0  = sub * 32;
  const float* vr = &vls[row * VST];

  // local inclusive prefix over own 32 columns (8x ds_read_b128)
  float q[32];
  {
    const float4* rb4 = (const float4*)(vr + 36 * sub);
    float run = 0.f;
#pragma unroll
    for (int k = 0; k < 8; ++k) {
      float4 vv = rb4[k];
      q[4 * k + 0] = run + vv.x;
      q[4 * k + 1] = q[4 * k + 0] + vv.y;
      q[4 * k + 2] = q[4 * k + 1] + vv.z;
      q[4 * k + 3] = q[4 * k + 2] + vv.w;
      run = q[4 * k + 3];
    }
  }
  // segmented (width-16) inclusive scan of chunk totals across the row
  {
    float tot = q[31];
    float s = tot;
#pragma unroll
    for (int d = 1; d < 16; d <<= 1) {
      float u = __shfl_up(s, d, 64);
      if (sub >= d) s += u;
    }
    float base = s - tot;   // exclusive prefix of preceding chunks
#pragma unroll
    for (int j = 0; j < 32; ++j) q[j] += base;   // q[j] = P[c0+j]
  }

  // box[c] = P[min(c+15,511)] - (c>=16 ? P[c-16] : 0); neighbors via shfl.
  const float* xr = xb + (size_t)(r0 + row) * IMG_W + c0;
  const float* tr = tb + (size_t)(r0 + row) * IMG_W + c0;
  const float inv_area = 1.0f / 961.0f;
  float aW = 0.f, aWB = 0.f, aI = 0.f, aU = 0.f;
#pragma unroll
  for (int jc = 0; jc < 8; ++jc) {
    float4 x4 = *(const float4*)(xr + 4 * jc);
    float4 t4 = *(const float4*)(tr + 4 * jc);
    float xa[4] = {x4.x, x4.y, x4.z, x4.w};
    float ta[4] = {t4.x, t4.y, t4.z, t4.w};
#pragma unroll
    for (int e = 0; e < 4; ++e) {
      const int j = 4 * jc + e;
      float hi, lo;
      if (j <= 16) {
        hi = q[j + 15];
      } else {
        float g = __shfl_down(q[j - 17], 1);
        hi = (sub == 15) ? q[31] : g;
      }
      if (j >= 16) {
        lo = q[j - 16];
      } else {
        float g = __shfl_up(q[j + 16], 1);
        lo = (sub == 0) ? 0.f : g;
      }
      float box = hi - lo;
      float tv = ta[e], xv = xa[e];
      float w   = fmaf(5.0f, fabsf(box * inv_area - tv), 1.0f);
      float ez  = __expf(-fabsf(xv));            // single exp
      float inv = 1.0f / (1.0f + ez);
      float p   = (xv >= 0.f) ? inv : ez * inv;  // sigmoid(x)
      float bce = fmaxf(xv, 0.f) - xv * tv + __logf(1.0f + ez);
      aW  += w;
      aWB = fmaf(w, bce, aWB);
      aI  = fmaf(p * tv, w, aI);
      aU  = fmaf(p + tv, w, aU);
    }
  }

  aW  = wave_reduce(aW);
  aWB = wave_reduce(aWB);
  aI  = wave_reduce(aI);
  aU  = wave_reduce(aU);
  const int wv = tid >> 6, ln = tid & 63;
  if (ln == 0) { red[wv][0] = aW; red[wv][1] = aWB; red[wv][2] = aI; red[wv][3] = aU; }
  __syncthreads();
  if (tid < 4)
    part[blockIdx.x * 4 + tid] = red[0][tid] + red[1][tid];
}

// ---- finalize: reduce 2048 block-partials -> scalar loss ----
__global__ void sloss_final(const float* __restrict__ part,
                            float* __restrict__ out) {
  __shared__ float s[128];
  int tid = threadIdx.x;          // 128 threads
  int img = tid >> 2, q = tid & 3;
  float v = 0.f;
#pragma unroll 4
  for (int g = 0; g < NGRP; ++g) v += part[((img << 6) + g) * 4 + q];
  s[tid] = v;
  __syncthreads();
  float loss = 0.f;
  if (tid < NB) {
    float aW  = s[tid * 4 + 0];
    float aWB = s[tid * 4 + 1];
    float aI  = s[tid * 4 + 2];
    float aU  = s[tid * 4 + 3];
    loss = aWB / aW + 1.0f - (aI + 1.0f) / (aU - aI + 1.0f);
  }
  loss = wave_reduce(loss);
  if (tid == 0) out[0] = loss * (1.0f / (float)NB);
}

extern "C" void kernel_launch(void* const* d_in, const int* in_sizes, int n_in,
                              void* d_out, int out_size, void* d_ws, size_t ws_size,
                              hipStream_t stream) {
  const float* x = (const float*)d_in[0];
  const float* t = (const float*)d_in[1];
  float* part = (float*)d_ws;     // 2048 blocks x 4 floats, fully overwritten

  sloss_main<<<NB * NGRP, NTH, 0, stream>>>(x, t, part);
  sloss_final<<<1, 128, 0, stream>>>(part, (float*)d_out);
}

// Round 6
// 122.658 us; speedup vs baseline: 1.0078x; 1.0078x over previous
//
#include <hip/hip_runtime.h>
#include <math.h>

// StructureLoss — fused kernel, R6: true 32-waves/CU occupancy.
// R5 post-mortem: R4 (4 blk x 4 waves) and R5 (8 blk x 2 waves) both cap at
// 16 waves/CU -> identical ~2.9 TB/s latency-bound plateau. R6: 256-thread
// blocks with RG=8 -> LDS 18.4 KB -> 8 blocks/CU x 4 waves = 32 waves/CU,
// VGPR held <= 64 via __launch_bounds__(256,8) (VGPR pool 2048/CU: 32 waves
// needs <=64). Stage 2: 8 rows x 32 subs of 16 cols, width-32 segmented scan.

#define IMG_H 512
#define IMG_W 512
#define NB    32
#define HW    (IMG_H * IMG_W)
#define RG    8               // output rows per block
#define NGRP  (IMG_H / RG)    // 64 row-groups per image
#define NTH   256
#define VST   576             // LDS row stride (floats); 512 + 16*4 skew

// skew +4 floats per 32-col chunk: chunk s occupies [36s, 36s+31], 16B-aligned
__device__ __forceinline__ int vidx(int c) { return c + 4 * (c >> 5); }

__device__ __forceinline__ float wave_reduce(float v) {
#pragma unroll
  for (int off = 32; off > 0; off >>= 1) v += __shfl_down(v, off, 64);
  return v;
}

__global__ __launch_bounds__(NTH, 8) void sloss_main(const float* __restrict__ x,
                                                     const float* __restrict__ t,
                                                     float* __restrict__ part) {
  __shared__ float vls[RG * VST];   // 8*576*4 = 18432 B -> 8 blocks/CU
  __shared__ float red[4][4];

  const int tid = threadIdx.x;
  const int img = blockIdx.x >> 6;
  const int grp = blockIdx.x & 63;
  const int r0  = grp * RG;
  const float* tb = t + (size_t)img * HW;
  const float* xb = x + (size_t)img * HW;

  // ---- Stage 1: vertical 31-row running sums; thread owns cols 2t,2t+1 ----
  {
    const float2* tc2 = (const float2*)tb + tid;   // row stride = 256 float2
    const int li = vidx(2 * tid);                  // pair stays in one chunk
    float sx = 0.f, sy = 0.f;
    if (grp >= 2 && grp <= 61) {                   // interior: no row guards
#pragma unroll
      for (int k = -15; k < 15; ++k) {
        float2 v = tc2[(r0 + k) * 256]; sx += v.x; sy += v.y;
      }
#pragma unroll
      for (int i = 0; i < RG; ++i) {
        float2 v = tc2[(r0 + i + 15) * 256]; sx += v.x; sy += v.y;
        vls[i * VST + li] = sx; vls[i * VST + li + 1] = sy;
        float2 u = tc2[(r0 + i - 15) * 256]; sx -= u.x; sy -= u.y;
      }
    } else {                                       // edge groups: guarded
#pragma unroll
      for (int k = -15; k < 15; ++k) {
        int r = r0 + k;
        if ((unsigned)r < IMG_H) { float2 v = tc2[r * 256]; sx += v.x; sy += v.y; }
      }
#pragma unroll
      for (int i = 0; i < RG; ++i) {
        int ra = r0 + i + 15;
        if (ra < IMG_H) { float2 v = tc2[ra * 256]; sx += v.x; sy += v.y; }
        vls[i * VST + li] = sx; vls[i * VST + li + 1] = sy;
        int rs = r0 + i - 15;
        if (rs >= 0) { float2 u = tc2[rs * 256]; sx -= u.x; sy -= u.y; }
      }
    }
  }
  __syncthreads();

  // ---- Stage 2: row prefix sums + box from registers + fused elementwise ----
  const int row = tid >> 5;                 // 0..7
  const int sub = tid & 31;                 // 0..31 (16-col chunk)
  const int c0  = sub * 16;
  const float* vr = &vls[row * VST];

  // local inclusive prefix over own 16 columns (4x ds_read_b128)
  float q[16];
  {
    const float4* rb4 = (const float4*)(vr + 36 * (sub >> 1) + 16 * (sub & 1));
    float run = 0.f;
#pragma unroll
    for (int k = 0; k < 4; ++k) {
      float4 vv = rb4[k];
      q[4 * k + 0] = run + vv.x;
      q[4 * k + 1] = q[4 * k + 0] + vv.y;
      q[4 * k + 2] = q[4 * k + 1] + vv.z;
      q[4 * k + 3] = q[4 * k + 2] + vv.w;
      run = q[4 * k + 3];
    }
  }
  // segmented (width-32) inclusive scan of chunk totals across the row
  {
    float tot = q[15];
    float s = tot;
#pragma unroll
    for (int d = 1; d < 32; d <<= 1) {
      float u = __shfl_up(s, d, 64);
      if (sub >= d) s += u;
    }
    float base = s - tot;   // exclusive prefix of preceding chunks
#pragma unroll
    for (int j = 0; j < 16; ++j) q[j] += base;   // q[j] = P[c0+j]
  }

  // box[c] = P[min(c+15,511)] - (c>=16 ? P[c-16] : 0); neighbors via +-1 shfl.
  // sub==31 / sub==0 clamps exactly mask cross-row shuffle contamination.
  const float* xr = xb + (size_t)(r0 + row) * IMG_W + c0;
  const float* tr = tb + (size_t)(r0 + row) * IMG_W + c0;
  const float inv_area = 1.0f / 961.0f;
  float aW = 0.f, aWB = 0.f, aI = 0.f, aU = 0.f;
#pragma unroll
  for (int jc = 0; jc < 4; ++jc) {
    float4 x4 = *(const float4*)(xr + 4 * jc);
    float4 t4 = *(const float4*)(tr + 4 * jc);
    float xa[4] = {x4.x, x4.y, x4.z, x4.w};
    float ta[4] = {t4.x, t4.y, t4.z, t4.w};
#pragma unroll
    for (int e = 0; e < 4; ++e) {
      const int j = 4 * jc + e;
      float hi, lo;
      if (j == 0) {
        hi = q[15];                          // P[c0+15]
      } else {
        float g = __shfl_down(q[j - 1], 1);  // next sub's P[c0+16 + j-1]
        hi = (sub == 31) ? q[15] : g;        // clamp to P[511]
      }
      {
        float g = __shfl_up(q[j], 1);        // prev sub's P[c0-16 + j]
        lo = (sub == 0) ? 0.f : g;
      }
      float box = hi - lo;
      float tv = ta[e], xv = xa[e];
      float w   = fmaf(5.0f, fabsf(box * inv_area - tv), 1.0f);
      float ez  = __expf(-fabsf(xv));            // single exp
      float inv = 1.0f / (1.0f + ez);
      float p   = (xv >= 0.f) ? inv : ez * inv;  // sigmoid(x)
      float bce = fmaxf(xv, 0.f) - xv * tv + __logf(1.0f + ez);
      aW  += w;
      aWB = fmaf(w, bce, aWB);
      aI  = fmaf(p * tv, w, aI);
      aU  = fmaf(p + tv, w, aU);
    }
  }

  aW  = wave_reduce(aW);
  aWB = wave_reduce(aWB);
  aI  = wave_reduce(aI);
  aU  = wave_reduce(aU);
  const int wv = tid >> 6, ln = tid & 63;
  if (ln == 0) { red[wv][0] = aW; red[wv][1] = aWB; red[wv][2] = aI; red[wv][3] = aU; }
  __syncthreads();
  if (tid < 4)
    part[blockIdx.x * 4 + tid] =
        red[0][tid] + red[1][tid] + red[2][tid] + red[3][tid];
}

// ---- finalize: reduce 2048 block-partials -> scalar loss ----
__global__ void sloss_final(const float* __restrict__ part,
                            float* __restrict__ out) {
  __shared__ float s[128];
  int tid = threadIdx.x;          // 128 threads
  int img = tid >> 2, q = tid & 3;
  float v = 0.f;
#pragma unroll 4
  for (int g = 0; g < NGRP; ++g) v += part[((img << 6) + g) * 4 + q];
  s[tid] = v;
  __syncthreads();
  float loss = 0.f;
  if (tid < NB) {
    float aW  = s[tid * 4 + 0];
    float aWB = s[tid * 4 + 1];
    float aI  = s[tid * 4 + 2];
    float aU  = s[tid * 4 + 3];
    loss = aWB / aW + 1.0f - (aI + 1.0f) / (aU - aI + 1.0f);
  }
  loss = wave_reduce(loss);
  if (tid == 0) out[0] = loss * (1.0f / (float)NB);
}

extern "C" void kernel_launch(void* const* d_in, const int* in_sizes, int n_in,
                              void* d_out, int out_size, void* d_ws, size_t ws_size,
                              hipStream_t stream) {
  const float* x = (const float*)d_in[0];
  const float* t = (const float*)d_in[1];
  float* part = (float*)d_ws;     // 2048 blocks x 4 floats, fully overwritten

  sloss_main<<<NB * NGRP, NTH, 0, stream>>>(x, t, part);
  sloss_final<<<1, 128, 0, stream>>>(part, (float*)d_out);
}

// Round 7
// 106.468 us; speedup vs baseline: 1.1611x; 1.1521x over previous
//
#include <hip/hip_runtime.h>
#include <math.h>

// StructureLoss — R7: explicit load-pipelining depth in stage 1.
// R4/R5/R6 post-mortem: main stuck at 42+-3 us (~2.6-3.0 TB/s) across 16 and
// 32 waves/CU -> not occupancy-bound; in-flight load depth per wave is the
// limiter (VGPR 52-60 -> ~4-8 loads in flight, vmcnt batch drains at ~900 cyc
// HBM latency). R7: launch_bounds(256,4) (128 VGPR) + warm-up as 3x10-row
// register batches w/ independent partial sums + 4-wide head/tail batches in
// the main loop + stage-2 x/t loads hoisted before the barrier + XCD swizzle
// (adjacent row-groups share an XCD L2 for halo reuse). RG=16 (best fetch).

#define IMG_H 512
#define IMG_W 512
#define NB    32
#define HW    (IMG_H * IMG_W)
#define RG    16              // output rows per block
#define NGRP  (IMG_H / RG)    // 32 row-groups per image
#define NTH   256
#define VST   576             // LDS row stride (floats); 512 + 16*4 skew

// skew +4 floats per 32-col chunk: chunk s occupies [36s, 36s+31], 16B-aligned
__device__ __forceinline__ int vidx(int c) { return c + 4 * (c >> 5); }

__device__ __forceinline__ float wave_reduce(float v) {
#pragma unroll
  for (int off = 32; off > 0; off >>= 1) v += __shfl_down(v, off, 64);
  return v;
}

__global__ __launch_bounds__(NTH, 4) void sloss_main(const float* __restrict__ x,
                                                     const float* __restrict__ t,
                                                     float* __restrict__ part) {
  __shared__ float vls[RG * VST];   // 16*576*4 = 36864 B -> 4 blocks/CU
  __shared__ float red[4][4];

  const int tid = threadIdx.x;
  // XCD swizzle: consecutive k on one XCD -> one image's groups stay in the
  // same XCD L2, halo rows between adjacent groups get L2 hits.
  const int xcd = blockIdx.x & 7;
  const int k   = blockIdx.x >> 3;        // 0..127
  const int img = (xcd << 2) | (k >> 5);  // 4 images per XCD
  const int grp = k & 31;
  const int r0  = grp * RG;
  const float* tb = t + (size_t)img * HW;
  const float* xb = x + (size_t)img * HW;

  // ---- Stage 1: vertical 31-row running sums; thread owns cols 2t,2t+1 ----
  {
    const float2* tc2 = (const float2*)tb + tid;   // row stride = 256 float2
    const int li = vidx(2 * tid);
    float sx, sy;
    if (grp >= 1 && grp <= 30) {                   // interior: no row guards
      // warm-up rows r0-15..r0+14 in 3 batches of 10; independent partials
      float2 w0[10], w1[10], w2[10];
#pragma unroll
      for (int j = 0; j < 10; ++j) w0[j] = tc2[(r0 - 15 + j) * 256];
#pragma unroll
      for (int j = 0; j < 10; ++j) w1[j] = tc2[(r0 - 5 + j) * 256];
#pragma unroll
      for (int j = 0; j < 10; ++j) w2[j] = tc2[(r0 + 5 + j) * 256];
      float ax = 0.f, ay = 0.f, bx2 = 0.f, by2 = 0.f, cx = 0.f, cy = 0.f;
#pragma unroll
      for (int j = 0; j < 10; ++j) { ax += w0[j].x; ay += w0[j].y; }
#pragma unroll
      for (int j = 0; j < 10; ++j) { bx2 += w1[j].x; by2 += w1[j].y; }
#pragma unroll
      for (int j = 0; j < 10; ++j) { cx += w2[j].x; cy += w2[j].y; }
      sx = ax + bx2 + cx; sy = ay + by2 + cy;
      // main loop: 4 rows/step, 8 loads issued as a batch ahead of the adds
#pragma unroll
      for (int c = 0; c < 4; ++c) {
        float2 hd[4], tl[4];
#pragma unroll
        for (int j = 0; j < 4; ++j) {
          hd[j] = tc2[(r0 + 4 * c + j + 15) * 256];
          tl[j] = tc2[(r0 + 4 * c + j - 15) * 256];
        }
#pragma unroll
        for (int j = 0; j < 4; ++j) {
          sx += hd[j].x; sy += hd[j].y;
          const int i = 4 * c + j;
          vls[i * VST + li] = sx; vls[i * VST + li + 1] = sy;
          sx -= tl[j].x; sy -= tl[j].y;
        }
      }
    } else {                                       // edge groups: guarded
      sx = 0.f; sy = 0.f;
#pragma unroll
      for (int kk = -15; kk < 15; ++kk) {
        int r = r0 + kk;
        if ((unsigned)r < IMG_H) { float2 v = tc2[r * 256]; sx += v.x; sy += v.y; }
      }
#pragma unroll
      for (int i = 0; i < RG; ++i) {
        int ra = r0 + i + 15;
        if (ra < IMG_H) { float2 v = tc2[ra * 256]; sx += v.x; sy += v.y; }
        vls[i * VST + li] = sx; vls[i * VST + li + 1] = sy;
        int rs = r0 + i - 15;
        if (rs >= 0) { float2 u = tc2[rs * 256]; sx -= u.x; sy -= u.y; }
      }
    }
  }

  // ---- hoist stage-2 x/t loads: overlap with barrier + prefix scan ----
  const int row = tid >> 4;                 // 0..15
  const int sub = tid & 15;                 // 0..15 (32-col chunk)
  const int c0  = sub * 32;
  const float* xr = xb + (size_t)(r0 + row) * IMG_W + c0;
  const float* tr = tb + (size_t)(r0 + row) * IMG_W + c0;
  float4 xg[8], tg[8];
#pragma unroll
  for (int jc = 0; jc < 8; ++jc) {
    xg[jc] = *(const float4*)(xr + 4 * jc);
    tg[jc] = *(const float4*)(tr + 4 * jc);
  }

  __syncthreads();

  // ---- Stage 2: row prefix sums + box from registers + fused elementwise ----
  const float* vr = &vls[row * VST];
  float q[32];
  {
    const float4* rb4 = (const float4*)(vr + 36 * sub);
    float run = 0.f;
#pragma unroll
    for (int kk = 0; kk < 8; ++kk) {
      float4 vv = rb4[kk];
      q[4 * kk + 0] = run + vv.x;
      q[4 * kk + 1] = q[4 * kk + 0] + vv.y;
      q[4 * kk + 2] = q[4 * kk + 1] + vv.z;
      q[4 * kk + 3] = q[4 * kk + 2] + vv.w;
      run = q[4 * kk + 3];
    }
  }
  // segmented (width-16) inclusive scan of chunk totals across the row
  {
    float tot = q[31];
    float s = tot;
#pragma unroll
    for (int d = 1; d < 16; d <<= 1) {
      float u = __shfl_up(s, d, 64);
      if (sub >= d) s += u;
    }
    float base = s - tot;
#pragma unroll
    for (int j = 0; j < 32; ++j) q[j] += base;   // q[j] = P[c0+j]
  }

  // box[c] = P[min(c+15,511)] - (c>=16 ? P[c-16] : 0); neighbors via shfl.
  const float inv_area = 1.0f / 961.0f;
  float aW = 0.f, aWB = 0.f, aI = 0.f, aU = 0.f;
#pragma unroll
  for (int jc = 0; jc < 8; ++jc) {
    float xa[4] = {xg[jc].x, xg[jc].y, xg[jc].z, xg[jc].w};
    float ta[4] = {tg[jc].x, tg[jc].y, tg[jc].z, tg[jc].w};
#pragma unroll
    for (int e = 0; e < 4; ++e) {
      const int j = 4 * jc + e;
      float hi, lo;
      if (j <= 16) {
        hi = q[j + 15];
      } else {
        float g = __shfl_down(q[j - 17], 1);
        hi = (sub == 15) ? q[31] : g;
      }
      {
        float g = __shfl_up(q[j + 16 < 32 ? j + 16 : j - 16], 1);
        lo = (j >= 16) ? q[j - 16] : ((sub == 0) ? 0.f : g);
      }
      float box = hi - lo;
      float tv = ta[e], xv = xa[e];
      float w   = fmaf(5.0f, fabsf(box * inv_area - tv), 1.0f);
      float ez  = __expf(-fabsf(xv));            // single exp
      float inv = 1.0f / (1.0f + ez);
      float p   = (xv >= 0.f) ? inv : ez * inv;  // sigmoid(x)
      float bce = fmaxf(xv, 0.f) - xv * tv + __logf(1.0f + ez);
      aW  += w;
      aWB = fmaf(w, bce, aWB);
      aI  = fmaf(p * tv, w, aI);
      aU  = fmaf(p + tv, w, aU);
    }
  }

  aW  = wave_reduce(aW);
  aWB = wave_reduce(aWB);
  aI  = wave_reduce(aI);
  aU  = wave_reduce(aU);
  const int wv = tid >> 6, ln = tid & 63;
  if (ln == 0) { red[wv][0] = aW; red[wv][1] = aWB; red[wv][2] = aI; red[wv][3] = aU; }
  __syncthreads();
  if (tid < 4)
    part[(img * NGRP + grp) * 4 + tid] =
        red[0][tid] + red[1][tid] + red[2][tid] + red[3][tid];
}

// ---- finalize: reduce 1024 block-partials -> scalar loss ----
__global__ void sloss_final(const float* __restrict__ part,
                            float* __restrict__ out) {
  __shared__ float s[128];
  int tid = threadIdx.x;          // 128 threads
  int img = tid >> 2, q = tid & 3;
  float v = 0.f;
#pragma unroll 4
  for (int g = 0; g < NGRP; ++g) v += part[((img << 5) + g) * 4 + q];
  s[tid] = v;
  __syncthreads();
  float loss = 0.f;
  if (tid < NB) {
    float aW  = s[tid * 4 + 0];
    float aWB = s[tid * 4 + 1];
    float aI  = s[tid * 4 + 2];
    float aU  = s[tid * 4 + 3];
    loss = aWB / aW + 1.0f - (aI + 1.0f) / (aU - aI + 1.0f);
  }
  loss = wave_reduce(loss);
  if (tid == 0) out[0] = loss * (1.0f / (float)NB);
}

extern "C" void kernel_launch(void* const* d_in, const int* in_sizes, int n_in,
                              void* d_out, int out_size, void* d_ws, size_t ws_size,
                              hipStream_t stream) {
  const float* x = (const float*)d_in[0];
  const float* t = (const float*)d_in[1];
  float* part = (float*)d_ws;     // 1024 x 4 floats, fully overwritten

  sloss_main<<<NB * NGRP, NTH, 0, stream>>>(x, t, part);
  sloss_final<<<1, 128, 0, stream>>>(part, (float*)d_out);
}